// Round 1
// baseline (1480.268 us; speedup 1.0000x reference)
//
#include <hip/hip_runtime.h>
#include <hip/hip_bf16.h>

typedef unsigned short u16;
typedef unsigned int   u32;
typedef __attribute__((ext_vector_type(8))) short bf16x8;   // 8 bf16 = 4 VGPR (MFMA A/B frag)
typedef __attribute__((ext_vector_type(4))) float f32x4;    // MFMA C/D frag
typedef __attribute__((ext_vector_type(4))) u16   u16x4;

__device__ __forceinline__ u16 f2bf(float f) {
  union { float f; u32 u; } v; v.f = f;
  u32 r = v.u + 0x7FFFu + ((v.u >> 16) & 1u);   // RNE
  return (u16)(r >> 16);
}
__device__ __forceinline__ float bf2f(u16 u) {
  union { u32 u; float f; } v; v.u = ((u32)u) << 16; return v.f;
}

#define GLL16(gptr, lptr)                                                            \
  __builtin_amdgcn_global_load_lds((const __attribute__((address_space(1))) u32*)(gptr), \
                                   (__attribute__((address_space(3))) u32*)(lptr), 16, 0, 0)

// ---------------------------------------------------------------- f32 -> bf16
__global__ __launch_bounds__(256) void cvt_bf16(const float* __restrict__ in,
                                                u16* __restrict__ out, int n4) {
  int i = blockIdx.x * blockDim.x + threadIdx.x;
  int stride = gridDim.x * blockDim.x;
  for (; i < n4; i += stride) {
    float4 v = ((const float4*)in)[i];
    u16x4 o = { f2bf(v.x), f2bf(v.y), f2bf(v.z), f2bf(v.w) };
    ((u16x4*)out)[i] = o;
  }
}

// ------------------------------------- values [16384][768] f32 -> Vt [768][16384] bf16
__global__ __launch_bounds__(256) void transpose_bf16(const float* __restrict__ in,
                                                      u16* __restrict__ out) {
  __shared__ u16 tile[64][65];
  int n0 = blockIdx.x * 64;          // over N=16384
  int d0 = blockIdx.y * 64;          // over D=768
  int t = threadIdx.x;
  int c = t & 63, r0 = t >> 6;       // r0 in 0..3
  for (int rr = 0; rr < 64; rr += 4) {
    int r = rr + r0;
    tile[c][r] = f2bf(in[(size_t)(n0 + r) * 768 + d0 + c]);
  }
  __syncthreads();
  for (int rr = 0; rr < 64; rr += 4) {
    int r = rr + r0;                 // d index
    out[(size_t)(d0 + r) * 16384 + n0 + c] = tile[r][c];
  }
}

// ---------------------------------------------------------------- GEMM1: projected = x·W^T + b
// x_bf16 [8192][1024], W_bf16 [768][1024] -> C f32 [8192][768]
// 128x128 tile, BK=32, 256 threads (4 waves, 2x2 of 64x64), m97-style
__global__ __launch_bounds__(256) void gemm1(const u16* __restrict__ A,
                                             const u16* __restrict__ B,
                                             const float* __restrict__ bias,
                                             float* __restrict__ C) {
  __shared__ u16 As[2][128 * 32];
  __shared__ u16 Bs[2][128 * 32];
  int t = threadIdx.x;
  int brow = blockIdx.x * 128, bcol = blockIdx.y * 128;
  int w = t >> 6, l = t & 63;
  int l15 = l & 15, l4 = l >> 4;
  int wr = (w >> 1) * 64, wc = (w & 1) * 64;
  f32x4 acc[4][4];
#pragma unroll
  for (int i = 0; i < 4; ++i)
#pragma unroll
    for (int j = 0; j < 4; ++j) acc[i][j] = f32x4{0.f, 0.f, 0.f, 0.f};

  auto stage = [&](int buf, int kt) {
#pragma unroll
    for (int i = 0; i < 2; ++i) {
      int id = t + i * 256;
      int row = id >> 2, c = id & 3;                    // 4 chunks of 16B per row
      int cs = (c ^ (row & 3)) * 8;                     // XOR-swizzled source chunk
      GLL16(A + (size_t)(brow + row) * 1024 + kt * 32 + cs, &As[buf][id * 8]);
      GLL16(B + (size_t)(bcol + row) * 1024 + kt * 32 + cs, &Bs[buf][id * 8]);
    }
  };
  stage(0, 0);
  for (int kt = 0; kt < 32; ++kt) {
    int buf = kt & 1;
    __syncthreads();
    if (kt < 31) stage(buf ^ 1, kt + 1);
    bf16x8 a[4], b[4];
#pragma unroll
    for (int mf = 0; mf < 4; ++mf) {
      int row = wr + mf * 16 + l15;
      a[mf] = *(const bf16x8*)&As[buf][row * 32 + ((l4 ^ (row & 3)) * 8)];
    }
#pragma unroll
    for (int nf = 0; nf < 4; ++nf) {
      int row = wc + nf * 16 + l15;
      b[nf] = *(const bf16x8*)&Bs[buf][row * 32 + ((l4 ^ (row & 3)) * 8)];
    }
#pragma unroll
    for (int mf = 0; mf < 4; ++mf)
#pragma unroll
      for (int nf = 0; nf < 4; ++nf)
        acc[mf][nf] = __builtin_amdgcn_mfma_f32_16x16x32_bf16(a[mf], b[nf], acc[mf][nf], 0, 0, 0);
  }
#pragma unroll
  for (int mf = 0; mf < 4; ++mf)
#pragma unroll
    for (int nf = 0; nf < 4; ++nf) {
      int col = bcol + wc + nf * 16 + l15;
      float bv = bias[col];
#pragma unroll
      for (int j = 0; j < 4; ++j) {
        int row = brow + wr + mf * 16 + l4 * 4 + j;
        C[(size_t)row * 768 + col] = acc[mf][nf][j] + bv;
      }
    }
}

// ---------------------------------------------------------------- row L2-normalize -> bf16
__global__ __launch_bounds__(256) void rownorm(const float* __restrict__ P,
                                               u16* __restrict__ pn) {
  int row = blockIdx.x, t = threadIdx.x;
  size_t base = (size_t)row * 768;
  float v0 = P[base + t], v1 = P[base + 256 + t], v2 = P[base + 512 + t];
  float ss = v0 * v0 + v1 * v1 + v2 * v2;
#pragma unroll
  for (int o = 32; o; o >>= 1) ss += __shfl_xor(ss, o);
  __shared__ float wsum[4];
  if ((t & 63) == 0) wsum[t >> 6] = ss;
  __syncthreads();
  float tot = wsum[0] + wsum[1] + wsum[2] + wsum[3];
  float inv = 1.0f / fmaxf(sqrtf(tot), 1e-12f);
  pn[base + t] = f2bf(v0 * inv);
  pn[base + 256 + t] = f2bf(v1 * inv);
  pn[base + 512 + t] = f2bf(v2 * inv);
}

// ---------------------------------------------------------------- fused attention
// Q=pn [8192][768] bf16, K [16384][768] bf16, Vt [768][16384] bf16.
// No max-tracking: logits = beta*cos_sim <= 5, exp can't overflow.
// BM=32 Q rows/block, KVBLK=128, 2-way KV split, 8 waves (512 thr).
// Swapped QK: S^T = mfma(K_frag_from_global, Q_frag_from_LDS) -> no K staging.
// Wave w: key-frag n_f = w (distinct, no dup); O cols [w*96, w*96+96).
__global__ __launch_bounds__(512, 4) void attn(const u16* __restrict__ pn,
                                               const u16* __restrict__ Kb,
                                               const u16* __restrict__ Vt,
                                               const float* __restrict__ beta_p,
                                               u16* __restrict__ Opart,
                                               float* __restrict__ lpart) {
  __shared__ u16 Qs[32 * 768];     // 48 KB, 16B-chunk XOR(row&7) swizzle
  __shared__ u16 Ps[32 * 128];     // 8 KB, same swizzle
  __shared__ float lred[8][2][16];
  int t = threadIdx.x;
  int w = t >> 6, l = t & 63;
  int l15 = l & 15, l4 = l >> 4;
  int qb = blockIdx.x, split = blockIdx.y;
  int qrow0 = qb * 32;
  float blog2e = beta_p[0] * 1.44269504089f;

  // stage Q tile (32 x 768): 3072 16B-chunks, 6 per thread
#pragma unroll
  for (int i = 0; i < 6; ++i) {
    int id = i * 512 + t;
    int row = id / 96, c = id % 96;
    GLL16(pn + (size_t)(qrow0 + row) * 768 + ((c ^ (row & 7)) * 8), &Qs[id * 8]);
  }
  f32x4 oacc[2][6];
#pragma unroll
  for (int m = 0; m < 2; ++m)
#pragma unroll
    for (int d = 0; d < 6; ++d) oacc[m][d] = f32x4{0.f, 0.f, 0.f, 0.f};
  float lsum[2] = {0.f, 0.f};
  __syncthreads();

  int kbase = split * 8192;
  const u16* vbase = Vt + (size_t)(w * 96 + l15) * 16384 + l4 * 8;

  for (int it = 0; it < 64; ++it) {
    int n0 = kbase + it * 128;
    // ---- QK^T (swapped): wave w covers keys n0+w*16 .. +15, all 32 q-rows
    f32x4 sacc0 = f32x4{0.f, 0.f, 0.f, 0.f};
    f32x4 sacc1 = f32x4{0.f, 0.f, 0.f, 0.f};
    const u16* kptr = Kb + (size_t)(n0 + w * 16 + l15) * 768 + l4 * 8;
    bf16x8 kcur = *(const bf16x8*)kptr;
#pragma unroll
    for (int ks = 0; ks < 24; ++ks) {
      bf16x8 knxt = kcur;
      if (ks < 23) knxt = *(const bf16x8*)(kptr + (ks + 1) * 32);
      int cq = ks * 4 + l4;
      int r1 = 16 + l15;
      bf16x8 q0 = *(const bf16x8*)&Qs[l15 * 768 + ((cq ^ (l15 & 7)) * 8)];
      bf16x8 q1 = *(const bf16x8*)&Qs[r1 * 768 + ((cq ^ (r1 & 7)) * 8)];
      sacc0 = __builtin_amdgcn_mfma_f32_16x16x32_bf16(kcur, q0, sacc0, 0, 0, 0);
      sacc1 = __builtin_amdgcn_mfma_f32_16x16x32_bf16(kcur, q1, sacc1, 0, 0, 0);
      kcur = knxt;
    }
    // ---- prefetch V k_f=0 (latency hides under exp/write/barrier)
    bf16x8 vf[6];
#pragma unroll
    for (int d = 0; d < 6; ++d) vf[d] = *(const bf16x8*)(vbase + (size_t)d * 16 * 16384 + n0);
    // ---- exp (no max needed), row-sum partials, P^T -> P store into LDS
#pragma unroll
    for (int m = 0; m < 2; ++m) {
      f32x4 s = (m == 0) ? sacc0 : sacc1;
      float p0 = exp2f(blog2e * s[0]), p1 = exp2f(blog2e * s[1]);
      float p2 = exp2f(blog2e * s[2]), p3 = exp2f(blog2e * s[3]);
      lsum[m] += (p0 + p1) + (p2 + p3);
      int qrow = m * 16 + l15;
      int c = w * 2 + (l4 >> 1);                       // 16B chunk of keys w*16+l4*4..+3
      u16x4 pw = { f2bf(p0), f2bf(p1), f2bf(p2), f2bf(p3) };
      *(u16x4*)&Ps[qrow * 128 + ((c ^ (qrow & 7)) * 8) + (l4 & 1) * 4] = pw;
    }
    __syncthreads();
    // ---- PV: O[qrow][d] += P[qrow][k] * Vt[d][k], k_f pipelined
#pragma unroll
    for (int kf = 0; kf < 4; ++kf) {
      bf16x8 vn[6];
#pragma unroll
      for (int d = 0; d < 6; ++d)
        vn[d] = (kf < 3) ? *(const bf16x8*)(vbase + (size_t)d * 16 * 16384 + n0 + (kf + 1) * 32)
                         : vf[d];
      int c = kf * 4 + l4;
      int r1 = 16 + l15;
      bf16x8 pa0 = *(const bf16x8*)&Ps[l15 * 128 + ((c ^ (l15 & 7)) * 8)];
      bf16x8 pa1 = *(const bf16x8*)&Ps[r1 * 128 + ((c ^ (r1 & 7)) * 8)];
#pragma unroll
      for (int d = 0; d < 6; ++d) {
        oacc[0][d] = __builtin_amdgcn_mfma_f32_16x16x32_bf16(pa0, vf[d], oacc[0][d], 0, 0, 0);
        oacc[1][d] = __builtin_amdgcn_mfma_f32_16x16x32_bf16(pa1, vf[d], oacc[1][d], 0, 0, 0);
      }
#pragma unroll
      for (int d = 0; d < 6; ++d) vf[d] = vn[d];
    }
    __syncthreads();   // protect Ps before next iter's writes
  }

  // ---- l reduction: lanes l, l+16, l+32, l+48 share a q-row
#pragma unroll
  for (int m = 0; m < 2; ++m) {
    float s = lsum[m];
    s += __shfl_xor(s, 16);
    s += __shfl_xor(s, 32);
    if (l4 == 0) lred[w][m][l15] = s;
  }
  __syncthreads();
  if (t < 32) {
    float s = 0.f;
#pragma unroll
    for (int ww = 0; ww < 8; ++ww) s += lred[ww][t >> 4][t & 15];
    lpart[split * 8192 + qrow0 + t] = s;
  }
  // ---- write unnormalized O partial (bf16)
#pragma unroll
  for (int m = 0; m < 2; ++m)
#pragma unroll
    for (int d = 0; d < 6; ++d) {
      int col = w * 96 + d * 16 + l15;
#pragma unroll
      for (int j = 0; j < 4; ++j) {
        int row = qrow0 + m * 16 + l4 * 4 + j;
        Opart[((size_t)split * 8192 + row) * 768 + col] = f2bf(oacc[m][d][j]);
      }
    }
}

// ---------------------------------------------------------------- final combine
__global__ __launch_bounds__(192) void combine(float* __restrict__ out,
                                               const u16* __restrict__ Opart,
                                               const float* __restrict__ lpart,
                                               const float* __restrict__ alpha_p) {
  int row = blockIdx.x, t = threadIdx.x;
  float scale = alpha_p[0] / (lpart[row] + lpart[8192 + row]);
  size_t base = (size_t)row * 768 + t * 4;
  u16x4 o0 = *(const u16x4*)&Opart[base];
  u16x4 o1 = *(const u16x4*)&Opart[(size_t)6291456 + base];
  float4 cur = *(float4*)&out[base];
  cur.x += (bf2f(o0[0]) + bf2f(o1[0])) * scale;
  cur.y += (bf2f(o0[1]) + bf2f(o1[1])) * scale;
  cur.z += (bf2f(o0[2]) + bf2f(o1[2])) * scale;
  cur.w += (bf2f(o0[3]) + bf2f(o1[3])) * scale;
  *(float4*)&out[base] = cur;
}

// ---------------------------------------------------------------- launch
extern "C" void kernel_launch(void* const* d_in, const int* in_sizes, int n_in,
                              void* d_out, int out_size, void* d_ws, size_t ws_size,
                              hipStream_t stream) {
  const float* x      = (const float*)d_in[0];   // [8192][1024]
  const float* W      = (const float*)d_in[1];   // [768][1024]
  const float* bias   = (const float*)d_in[2];   // [768]
  const float* keys   = (const float*)d_in[3];   // [16384][768]
  const float* values = (const float*)d_in[4];   // [16384][768]
  const float* beta   = (const float*)d_in[5];
  const float* alpha  = (const float*)d_in[6];
  float* out = (float*)d_out;

  char* ws = (char*)d_ws;
  u16* xb    = (u16*)(ws + 0);            // 16,777,216 B
  u16* Wb    = (u16*)(ws + 16777216);     //  1,572,864 B
  u16* Kb    = (u16*)(ws + 18350080);     // 25,165,824 B
  u16* Vtb   = (u16*)(ws + 43515904);     // 25,165,824 B
  u16* pn    = (u16*)(ws + 68681728);     // 12,582,912 B
  u16* Opart = (u16*)(ws + 81264640);     // 25,165,824 B
  float* lp  = (float*)(ws + 106430464);  //     65,536 B   (total 106,496,000)

  cvt_bf16<<<2048, 256, 0, stream>>>(x, xb, 8192 * 1024 / 4);
  cvt_bf16<<<768, 256, 0, stream>>>(W, Wb, 768 * 1024 / 4);
  cvt_bf16<<<2048, 256, 0, stream>>>(keys, Kb, 16384 * 768 / 4);
  transpose_bf16<<<dim3(256, 12), 256, 0, stream>>>(values, Vtb);
  gemm1<<<dim3(64, 6), 256, 0, stream>>>(xb, Wb, bias, out);
  rownorm<<<8192, 256, 0, stream>>>(out, pn);
  attn<<<dim3(256, 2), 512, 0, stream>>>(pn, Kb, Vtb, beta, Opart, lp);
  combine<<<8192, 192, 0, stream>>>(out, Opart, lp, alpha);
}

// Round 3
// 853.859 us; speedup vs baseline: 1.7336x; 1.7336x over previous
//
#include <hip/hip_runtime.h>
#include <hip/hip_bf16.h>
#include <hip/hip_fp8.h>

typedef unsigned char  u8;
typedef unsigned short u16;
typedef unsigned int   u32;
typedef unsigned long long u64;
typedef __attribute__((ext_vector_type(8)))  short bf16x8;
typedef __attribute__((ext_vector_type(4)))  float f32x4;
typedef __attribute__((ext_vector_type(16))) float f32x16;
typedef __attribute__((ext_vector_type(4)))  u16   u16x4;

__device__ __forceinline__ u16 f2bf(float f) {
  union { float f; u32 u; } v; v.f = f;
  u32 r = v.u + 0x7FFFu + ((v.u >> 16) & 1u);   // RNE
  return (u16)(r >> 16);
}

// pack 2 floats into fp8 e4m3 pair (WORD=false: low 16 bits of old; true: high)
template <bool WORD>
__device__ __forceinline__ u32 pk_fp8(float a, float b, u32 old) {
#if __has_builtin(__builtin_amdgcn_cvt_pk_fp8_f32)
  return (u32)__builtin_amdgcn_cvt_pk_fp8_f32(a, b, (int)old, WORD);
#else
  __hip_fp8_e4m3 x(a), y(b);
  u32 v = (u32)x.__x | ((u32)y.__x << 8);
  return WORD ? ((old & 0xFFFFu) | (v << 16)) : ((old & 0xFFFF0000u) | v);
#endif
}

#define GLL16(gptr, lptr)                                                            \
  __builtin_amdgcn_global_load_lds((const __attribute__((address_space(1))) u32*)(gptr), \
                                   (__attribute__((address_space(3))) u32*)(lptr), 16, 0, 0)

#define BARRIER_LGKM() do { asm volatile("s_waitcnt lgkmcnt(0)" ::: "memory"); \
                            __builtin_amdgcn_s_barrier(); } while (0)

// ---------------------------------------------------------------- f32 -> bf16
__global__ __launch_bounds__(256) void cvt_bf16(const float* __restrict__ in,
                                                u16* __restrict__ out, int n4) {
  int i = blockIdx.x * blockDim.x + threadIdx.x;
  int stride = gridDim.x * blockDim.x;
  for (; i < n4; i += stride) {
    float4 v = ((const float4*)in)[i];
    u16x4 o = { f2bf(v.x), f2bf(v.y), f2bf(v.z), f2bf(v.w) };
    ((u16x4*)out)[i] = o;
  }
}

// ------------------- keys [16384][768] f32 -> Kf2 fp8, layout [d8=96][key=16384][8B]
// Kf2[d8][key][e] = fp8(keys[key][d8*8+e])
__global__ __launch_bounds__(256) void buildK(const float* __restrict__ in,
                                              u8* __restrict__ out) {
  __shared__ float tile[64][65];
  int kt = blockIdx.x;            // 64 keys per block
  int t = threadIdx.x;
  int r0 = t >> 6, c = t & 63;
  for (int dc = 0; dc < 12; ++dc) {
    if (dc) __syncthreads();
#pragma unroll
    for (int i = 0; i < 16; ++i) {
      int r = i * 4 + r0;
      tile[r][c] = in[(size_t)(kt * 64 + r) * 768 + dc * 64 + c];
    }
    __syncthreads();
    int d8l = t >> 5, kl = t & 31;
#pragma unroll
    for (int j = 0; j < 2; ++j) {
      int key = j * 32 + kl;
      float v0 = tile[key][d8l * 8 + 0], v1 = tile[key][d8l * 8 + 1];
      float v2 = tile[key][d8l * 8 + 2], v3 = tile[key][d8l * 8 + 3];
      float v4 = tile[key][d8l * 8 + 4], v5 = tile[key][d8l * 8 + 5];
      float v6 = tile[key][d8l * 8 + 6], v7 = tile[key][d8l * 8 + 7];
      u32 lo = pk_fp8<false>(v0, v1, 0u); lo = pk_fp8<true>(v2, v3, lo);
      u32 hi = pk_fp8<false>(v4, v5, 0u); hi = pk_fp8<true>(v6, v7, hi);
      uint2 val = { lo, hi };
      *(uint2*)(out + (size_t)(dc * 8 + d8l) * 131072 + (size_t)(kt * 64 + key) * 8) = val;
    }
  }
}

// ------------------- values [16384][768] f32 -> Vtf fp8, layout [k8=2048][d=768][8B]
// Vtf[k8][d][e] = fp8(values[k8*8+e][d])
__global__ __launch_bounds__(256) void buildV(const float* __restrict__ in,
                                              u8* __restrict__ out) {
  __shared__ float tile[64][65];
  int kt = blockIdx.x;            // 64 keys per block
  int t = threadIdx.x;
  int r0 = t >> 6, c = t & 63;
  for (int dc = 0; dc < 12; ++dc) {
    if (dc) __syncthreads();
#pragma unroll
    for (int i = 0; i < 16; ++i) {
      int r = i * 4 + r0;
      tile[r][c] = in[(size_t)(kt * 64 + r) * 768 + dc * 64 + c];
    }
    __syncthreads();
    int sub = t >> 5, dl = t & 31;
#pragma unroll
    for (int j = 0; j < 2; ++j) {
      int d = j * 32 + dl;
      float v0 = tile[sub * 8 + 0][d], v1 = tile[sub * 8 + 1][d];
      float v2 = tile[sub * 8 + 2][d], v3 = tile[sub * 8 + 3][d];
      float v4 = tile[sub * 8 + 4][d], v5 = tile[sub * 8 + 5][d];
      float v6 = tile[sub * 8 + 6][d], v7 = tile[sub * 8 + 7][d];
      u32 lo = pk_fp8<false>(v0, v1, 0u); lo = pk_fp8<true>(v2, v3, lo);
      u32 hi = pk_fp8<false>(v4, v5, 0u); hi = pk_fp8<true>(v6, v7, hi);
      uint2 val = { lo, hi };
      *(uint2*)(out + (size_t)(kt * 8 + sub) * 6144 + (size_t)(dc * 64 + d) * 8) = val;
    }
  }
}

// ---------------------------------------------------------------- GEMM1 (bf16)
__global__ __launch_bounds__(256) void gemm1(const u16* __restrict__ A,
                                             const u16* __restrict__ B,
                                             const float* __restrict__ bias,
                                             float* __restrict__ C) {
  __shared__ u16 As[2][128 * 32];
  __shared__ u16 Bs[2][128 * 32];
  int t = threadIdx.x;
  int brow = blockIdx.x * 128, bcol = blockIdx.y * 128;
  int w = t >> 6, l = t & 63;
  int l15 = l & 15, l4 = l >> 4;
  int wr = (w >> 1) * 64, wc = (w & 1) * 64;
  f32x4 acc[4][4];
#pragma unroll
  for (int i = 0; i < 4; ++i)
#pragma unroll
    for (int j = 0; j < 4; ++j) acc[i][j] = f32x4{0.f, 0.f, 0.f, 0.f};

  auto stage = [&](int buf, int kt) {
#pragma unroll
    for (int i = 0; i < 2; ++i) {
      int id = t + i * 256;
      int row = id >> 2, c = id & 3;
      int cs = (c ^ (row & 3)) * 8;
      GLL16(A + (size_t)(brow + row) * 1024 + kt * 32 + cs, &As[buf][id * 8]);
      GLL16(B + (size_t)(bcol + row) * 1024 + kt * 32 + cs, &Bs[buf][id * 8]);
    }
  };
  stage(0, 0);
  for (int kt = 0; kt < 32; ++kt) {
    int buf = kt & 1;
    __syncthreads();
    if (kt < 31) stage(buf ^ 1, kt + 1);
    bf16x8 a[4], b[4];
#pragma unroll
    for (int mf = 0; mf < 4; ++mf) {
      int row = wr + mf * 16 + l15;
      a[mf] = *(const bf16x8*)&As[buf][row * 32 + ((l4 ^ (row & 3)) * 8)];
    }
#pragma unroll
    for (int nf = 0; nf < 4; ++nf) {
      int row = wc + nf * 16 + l15;
      b[nf] = *(const bf16x8*)&Bs[buf][row * 32 + ((l4 ^ (row & 3)) * 8)];
    }
#pragma unroll
    for (int mf = 0; mf < 4; ++mf)
#pragma unroll
      for (int nf = 0; nf < 4; ++nf)
        acc[mf][nf] = __builtin_amdgcn_mfma_f32_16x16x32_bf16(a[mf], b[nf], acc[mf][nf], 0, 0, 0);
  }
#pragma unroll
  for (int mf = 0; mf < 4; ++mf)
#pragma unroll
    for (int nf = 0; nf < 4; ++nf) {
      int col = bcol + wc + nf * 16 + l15;
      float bv = bias[col];
#pragma unroll
      for (int j = 0; j < 4; ++j) {
        int row = brow + wr + mf * 16 + l4 * 4 + j;
        C[(size_t)row * 768 + col] = acc[mf][nf][j] + bv;
      }
    }
}

// ---------------------------------------------------------------- row L2-normalize -> fp8
__global__ __launch_bounds__(384) void rownorm8(const float* __restrict__ P,
                                                u8* __restrict__ pn8) {
  int row = blockIdx.x, t = threadIdx.x;
  size_t base = (size_t)row * 768;
  float2 v = *(const float2*)&P[base + 2 * t];
  float ss = v.x * v.x + v.y * v.y;
#pragma unroll
  for (int o = 32; o; o >>= 1) ss += __shfl_xor(ss, o);
  __shared__ float wsum[6];
  if ((t & 63) == 0) wsum[t >> 6] = ss;
  __syncthreads();
  float tot = wsum[0] + wsum[1] + wsum[2] + wsum[3] + wsum[4] + wsum[5];
  float inv = 1.0f / fmaxf(sqrtf(tot), 1e-12f);
  u32 pk = pk_fp8<false>(v.x * inv, v.y * inv, 0u);
  *(u16*)(pn8 + base + 2 * t) = (u16)(pk & 0xFFFFu);
}

// ---------------------------------------------------------------- fused attention, fp8
// Q=pn8 [8192][768] fp8 row-major; Kf2 [96 d8][16384 key][8B]; Vtf [2048 k8][768 d][8B].
// BM=64 q-rows/block, KVBLK=256, nsplit=2, 8 waves (512 thr), 32x32x16 fp8 MFMA.
// Logits = beta*cos_sim <= 5 -> no max tracking; accumulate unnormalized O and l.
// QK (swapped): Sacc = mfma(A=K, B=Q) -> S^T [key][q]; P through LDS; PV: O = mfma(A=P, B=V).
__global__ __launch_bounds__(512, 2) void attn(const u8* __restrict__ pn8,
                                               const u8* __restrict__ Kf2,
                                               const u8* __restrict__ Vtf,
                                               const float* __restrict__ beta_p,
                                               u16* __restrict__ Opart,
                                               float* __restrict__ lpart) {
  __shared__ long Qlds[96 * 64];   // [c8][q] : 8 consecutive d of one q-row, conflict-free
  __shared__ long Ps[32 * 64];     // [kc8][q] : 8 consecutive keys of one q-col
  __shared__ float lred[8][64];
  int t = threadIdx.x;
  int w = t >> 6, l = t & 63;
  int ql = l & 31, hi = l >> 5;
  int split = blockIdx.x, qb = blockIdx.y;
  int qrow0 = qb * 64;
  float blog2e = beta_p[0] * 1.44269504089f;

  // ---- stage Q [64 q][768 d] fp8 into [c8][q] layout (once)
#pragma unroll
  for (int i = 0; i < 12; ++i) {
    int id = i * 512 + t;          // id = c8*64 + q
    int c8 = id >> 6, q = id & 63;
    Qlds[id] = *(const long*)(pn8 + (size_t)(qrow0 + q) * 768 + (size_t)c8 * 8);
  }

  f32x16 oacc[2][3];
#pragma unroll
  for (int mq = 0; mq < 2; ++mq)
#pragma unroll
    for (int nd = 0; nd < 3; ++nd) oacc[mq][nd] = (f32x16)0.0f;
  float lsum0 = 0.f, lsum1 = 0.f;

  int kbase = split * 8192;
  int key0 = w * 32 + ql;                       // this wave's key lane (rel. to tile)
  int d0 = w * 96 + ql;                         // this wave's d lane base for PV
  const long* Kbase_l = (const long*)Kf2 + (size_t)hi * 16384 + key0 + kbase;
  const long* Vbase_l = (const long*)Vtf + (size_t)(kbase >> 3) * 768 + (size_t)hi * 768 + d0;

  __syncthreads();

  for (int it = 0; it < 32; ++it) {
    int n0 = it * 256;                          // tile-relative key offset
    const long* kp = Kbase_l + n0;              // + key offset (longs == 8B units)
    const long* vp = Vbase_l + (size_t)(n0 >> 3) * 768;

    // ---------- QK^T (swapped): wave w -> keys [n0+w*32, +32), all 64 q
    f32x16 sacc0 = (f32x16)0.0f;
    f32x16 sacc1 = (f32x16)0.0f;
    long kbuf[8];
#pragma unroll
    for (int i = 0; i < 8; ++i) kbuf[i] = kp[(size_t)i * 32768];
#pragma unroll
    for (int ks = 0; ks < 48; ++ks) {
      long kv = kbuf[ks & 7];
      if (ks < 40) kbuf[ks & 7] = kp[(size_t)(ks + 8) * 32768];
      long q0 = Qlds[(ks * 2 + hi) * 64 + ql];
      long q1 = Qlds[(ks * 2 + hi) * 64 + ql + 32];
      sacc0 = __builtin_amdgcn_mfma_f32_32x32x16_fp8_fp8(kv, q0, sacc0, 0, 0, 0);
      sacc1 = __builtin_amdgcn_mfma_f32_32x32x16_fp8_fp8(kv, q1, sacc1, 0, 0, 0);
    }

    // ---------- exp (no max), lsum, pack fp8 -> Ps [kc8][q]
    // sacc row r (reg): key = n0 + w*32 + (r&3) + 8*(r>>2) + 4*hi ; col q = ql (+32 for sacc1)
#pragma unroll
    for (int qf = 0; qf < 2; ++qf) {
      int q = ql + qf * 32;
      float lacc = 0.f;
#pragma unroll
      for (int rg = 0; rg < 4; ++rg) {
        float p0, p1, p2, p3;
        if (qf == 0) {
          p0 = exp2f(blog2e * sacc0[rg * 4 + 0]); p1 = exp2f(blog2e * sacc0[rg * 4 + 1]);
          p2 = exp2f(blog2e * sacc0[rg * 4 + 2]); p3 = exp2f(blog2e * sacc0[rg * 4 + 3]);
        } else {
          p0 = exp2f(blog2e * sacc1[rg * 4 + 0]); p1 = exp2f(blog2e * sacc1[rg * 4 + 1]);
          p2 = exp2f(blog2e * sacc1[rg * 4 + 2]); p3 = exp2f(blog2e * sacc1[rg * 4 + 3]);
        }
        lacc += (p0 + p1) + (p2 + p3);
        u32 pk = pk_fp8<false>(p0, p1, 0u); pk = pk_fp8<true>(p2, p3, pk);
        // keys kb..kb+3 with kb = w*32 + rg*8 + 4*hi  ->  kc8 = w*4+rg, byte off 4*hi
        ((u32*)Ps)[(w * 4 + rg) * 128 + q * 2 + hi] = pk;
      }
      if (qf == 0) lsum0 += lacc; else lsum1 += lacc;
    }
    BARRIER_LGKM();   // P visible to all waves

    // ---------- PV: O[64 q][96 d per wave] += P * V
    long vbuf[6];
#pragma unroll
    for (int i = 0; i < 3; ++i) { vbuf[i] = vp[i * 32]; vbuf[3 + i] = vp[1536 + i * 32]; }
#pragma unroll
    for (int ksv = 0; ksv < 16; ++ksv) {
      int st = (ksv & 1) * 3;
      long v0 = vbuf[st + 0], v1 = vbuf[st + 1], v2 = vbuf[st + 2];
      if (ksv < 14) {
#pragma unroll
        for (int i = 0; i < 3; ++i) vbuf[st + i] = vp[(size_t)(ksv + 2) * 1536 + i * 32];
      }
      long pa0 = Ps[(ksv * 2 + hi) * 64 + ql];
      long pa1 = Ps[(ksv * 2 + hi) * 64 + ql + 32];
      oacc[0][0] = __builtin_amdgcn_mfma_f32_32x32x16_fp8_fp8(pa0, v0, oacc[0][0], 0, 0, 0);
      oacc[0][1] = __builtin_amdgcn_mfma_f32_32x32x16_fp8_fp8(pa0, v1, oacc[0][1], 0, 0, 0);
      oacc[0][2] = __builtin_amdgcn_mfma_f32_32x32x16_fp8_fp8(pa0, v2, oacc[0][2], 0, 0, 0);
      oacc[1][0] = __builtin_amdgcn_mfma_f32_32x32x16_fp8_fp8(pa1, v0, oacc[1][0], 0, 0, 0);
      oacc[1][1] = __builtin_amdgcn_mfma_f32_32x32x16_fp8_fp8(pa1, v1, oacc[1][1], 0, 0, 0);
      oacc[1][2] = __builtin_amdgcn_mfma_f32_32x32x16_fp8_fp8(pa1, v2, oacc[1][2], 0, 0, 0);
    }
    BARRIER_LGKM();   // Ps reads drained before next iter rewrites
  }

  // ---- l reduction: lane l and l^32 share q=ql; wave covers its 32 keys fully
  {
    float s0 = lsum0 + __shfl_xor(lsum0, 32);
    float s1 = lsum1 + __shfl_xor(lsum1, 32);
    if (l < 32) { lred[w][ql] = s0; lred[w][ql + 32] = s1; }
  }
  __syncthreads();
  if (t < 64) {
    float s = 0.f;
#pragma unroll
    for (int ww = 0; ww < 8; ++ww) s += lred[ww][t];
    lpart[split * 8192 + qrow0 + t] = s;
  }

  // ---- write unnormalized O partial (bf16): row = mq*32 + (r&3)+8*(r>>2)+4*hi, col = d0+nd*32
#pragma unroll
  for (int mq = 0; mq < 2; ++mq)
#pragma unroll
    for (int nd = 0; nd < 3; ++nd)
#pragma unroll
      for (int r = 0; r < 16; ++r) {
        int row = qrow0 + mq * 32 + (r & 3) + 8 * (r >> 2) + 4 * hi;
        int col = w * 96 + nd * 32 + ql;
        Opart[((size_t)split * 8192 + row) * 768 + col] = f2bf(oacc[mq][nd][r]);
      }
}

// ---------------------------------------------------------------- final combine
__global__ __launch_bounds__(192) void combine(float* __restrict__ out,
                                               const u16* __restrict__ Opart,
                                               const float* __restrict__ lpart,
                                               const float* __restrict__ alpha_p) {
  int row = blockIdx.x, t = threadIdx.x;
  float scale = alpha_p[0] / (lpart[row] + lpart[8192 + row]);
  size_t base = (size_t)row * 768 + t * 4;
  u16x4 o0 = *(const u16x4*)&Opart[base];
  u16x4 o1 = *(const u16x4*)&Opart[(size_t)6291456 + base];
  float4 cur = *(float4*)&out[base];
  union { u32 u; float f; } c0, c1, c2, c3, d0_, d1_, d2_, d3_;
  c0.u = (u32)o0[0] << 16; c1.u = (u32)o0[1] << 16; c2.u = (u32)o0[2] << 16; c3.u = (u32)o0[3] << 16;
  d0_.u = (u32)o1[0] << 16; d1_.u = (u32)o1[1] << 16; d2_.u = (u32)o1[2] << 16; d3_.u = (u32)o1[3] << 16;
  cur.x += (c0.f + d0_.f) * scale;
  cur.y += (c1.f + d1_.f) * scale;
  cur.z += (c2.f + d2_.f) * scale;
  cur.w += (c3.f + d3_.f) * scale;
  *(float4*)&out[base] = cur;
}

// ---------------------------------------------------------------- launch
extern "C" void kernel_launch(void* const* d_in, const int* in_sizes, int n_in,
                              void* d_out, int out_size, void* d_ws, size_t ws_size,
                              hipStream_t stream) {
  const float* x      = (const float*)d_in[0];   // [8192][1024]
  const float* W      = (const float*)d_in[1];   // [768][1024]
  const float* bias   = (const float*)d_in[2];   // [768]
  const float* keys   = (const float*)d_in[3];   // [16384][768]
  const float* values = (const float*)d_in[4];   // [16384][768]
  const float* beta   = (const float*)d_in[5];
  const float* alpha  = (const float*)d_in[6];
  float* out = (float*)d_out;

  char* ws = (char*)d_ws;
  u16* xb    = (u16*)(ws + 0);            // 16,777,216 B
  u16* Wb    = (u16*)(ws + 16777216);     //  1,572,864 B
  u8*  Kf2   = (u8*) (ws + 18350080);     // 12,582,912 B
  u8*  Vtf   = (u8*) (ws + 30932992);     // 12,582,912 B
  u8*  pn8   = (u8*) (ws + 43515904);     //  6,291,456 B
  u16* Opart = (u16*)(ws + 49807360);     // 25,165,824 B
  float* lp  = (float*)(ws + 74973184);   //     65,536 B   (total 75,038,720)

  cvt_bf16<<<2048, 256, 0, stream>>>(x, xb, 8192 * 1024 / 4);
  cvt_bf16<<<768, 256, 0, stream>>>(W, Wb, 768 * 1024 / 4);
  buildK<<<256, 256, 0, stream>>>(keys, Kf2);
  buildV<<<256, 256, 0, stream>>>(values, Vtf);
  gemm1<<<dim3(64, 6), 256, 0, stream>>>(xb, Wb, bias, out);
  rownorm8<<<8192, 384, 0, stream>>>(out, pn8);
  attn<<<dim3(2, 128), 512, 0, stream>>>(pn8, Kf2, Vtf, beta, Opart, lp);
  combine<<<8192, 192, 0, stream>>>(out, Opart, lp, alpha);
}

// Round 4
// 476.345 us; speedup vs baseline: 3.1076x; 1.7925x over previous
//
#include <hip/hip_runtime.h>
#include <hip/hip_bf16.h>
#include <hip/hip_fp8.h>

typedef unsigned char  u8;
typedef unsigned short u16;
typedef unsigned int   u32;
typedef unsigned long long u64;
typedef __attribute__((ext_vector_type(8)))  short bf16x8;
typedef __attribute__((ext_vector_type(4)))  float f32x4;
typedef __attribute__((ext_vector_type(16))) float f32x16;
typedef __attribute__((ext_vector_type(4)))  u16   u16x4;

__device__ __forceinline__ u16 f2bf(float f) {
  union { float f; u32 u; } v; v.f = f;
  u32 r = v.u + 0x7FFFu + ((v.u >> 16) & 1u);   // RNE
  return (u16)(r >> 16);
}

// pack 2 floats into fp8 e4m3 pair (WORD=false: low 16 bits of old; true: high)
template <bool WORD>
__device__ __forceinline__ u32 pk_fp8(float a, float b, u32 old) {
#if __has_builtin(__builtin_amdgcn_cvt_pk_fp8_f32)
  return (u32)__builtin_amdgcn_cvt_pk_fp8_f32(a, b, (int)old, WORD);
#else
  __hip_fp8_e4m3 x(a), y(b);
  u32 v = (u32)x.__x | ((u32)y.__x << 8);
  return WORD ? ((old & 0xFFFFu) | (v << 16)) : ((old & 0xFFFF0000u) | v);
#endif
}

#define GLL16(gptr, lptr)                                                            \
  __builtin_amdgcn_global_load_lds((const __attribute__((address_space(1))) u32*)(gptr), \
                                   (__attribute__((address_space(3))) u32*)(lptr), 16, 0, 0)

#define BARRIER_LGKM() do { asm volatile("s_waitcnt lgkmcnt(0)" ::: "memory"); \
                            __builtin_amdgcn_s_barrier(); } while (0)

// ---------------------------------------------------------------- f32 -> bf16
__global__ __launch_bounds__(256) void cvt_bf16(const float* __restrict__ in,
                                                u16* __restrict__ out, int n4) {
  int i = blockIdx.x * blockDim.x + threadIdx.x;
  int stride = gridDim.x * blockDim.x;
  for (; i < n4; i += stride) {
    float4 v = ((const float4*)in)[i];
    u16x4 o = { f2bf(v.x), f2bf(v.y), f2bf(v.z), f2bf(v.w) };
    ((u16x4*)out)[i] = o;
  }
}

// ------------------- keys [16384][768] f32 -> Kf2 fp8, layout [d8=96][key=16384][8B]
__global__ __launch_bounds__(256) void buildK(const float* __restrict__ in,
                                              u8* __restrict__ out) {
  __shared__ float tile[64][65];
  int kt = blockIdx.x;            // 64 keys per block
  int t = threadIdx.x;
  int r0 = t >> 6, c = t & 63;
  for (int dc = 0; dc < 12; ++dc) {
    if (dc) __syncthreads();
#pragma unroll
    for (int i = 0; i < 16; ++i) {
      int r = i * 4 + r0;
      tile[r][c] = in[(size_t)(kt * 64 + r) * 768 + dc * 64 + c];
    }
    __syncthreads();
    int d8l = t >> 5, kl = t & 31;
#pragma unroll
    for (int j = 0; j < 2; ++j) {
      int key = j * 32 + kl;
      float v0 = tile[key][d8l * 8 + 0], v1 = tile[key][d8l * 8 + 1];
      float v2 = tile[key][d8l * 8 + 2], v3 = tile[key][d8l * 8 + 3];
      float v4 = tile[key][d8l * 8 + 4], v5 = tile[key][d8l * 8 + 5];
      float v6 = tile[key][d8l * 8 + 6], v7 = tile[key][d8l * 8 + 7];
      u32 lo = pk_fp8<false>(v0, v1, 0u); lo = pk_fp8<true>(v2, v3, lo);
      u32 hi = pk_fp8<false>(v4, v5, 0u); hi = pk_fp8<true>(v6, v7, hi);
      uint2 val = { lo, hi };
      *(uint2*)(out + (size_t)(dc * 8 + d8l) * 131072 + (size_t)(kt * 64 + key) * 8) = val;
    }
  }
}

// ------------------- values [16384][768] f32 -> Vtf fp8, layout [k8=2048][d=768][8B]
__global__ __launch_bounds__(256) void buildV(const float* __restrict__ in,
                                              u8* __restrict__ out) {
  __shared__ float tile[64][65];
  int kt = blockIdx.x;            // 64 keys per block
  int t = threadIdx.x;
  int r0 = t >> 6, c = t & 63;
  for (int dc = 0; dc < 12; ++dc) {
    if (dc) __syncthreads();
#pragma unroll
    for (int i = 0; i < 16; ++i) {
      int r = i * 4 + r0;
      tile[r][c] = in[(size_t)(kt * 64 + r) * 768 + dc * 64 + c];
    }
    __syncthreads();
    int sub = t >> 5, dl = t & 31;
#pragma unroll
    for (int j = 0; j < 2; ++j) {
      int d = j * 32 + dl;
      float v0 = tile[sub * 8 + 0][d], v1 = tile[sub * 8 + 1][d];
      float v2 = tile[sub * 8 + 2][d], v3 = tile[sub * 8 + 3][d];
      float v4 = tile[sub * 8 + 4][d], v5 = tile[sub * 8 + 5][d];
      float v6 = tile[sub * 8 + 6][d], v7 = tile[sub * 8 + 7][d];
      u32 lo = pk_fp8<false>(v0, v1, 0u); lo = pk_fp8<true>(v2, v3, lo);
      u32 hi = pk_fp8<false>(v4, v5, 0u); hi = pk_fp8<true>(v6, v7, hi);
      uint2 val = { lo, hi };
      *(uint2*)(out + (size_t)(kt * 8 + sub) * 6144 + (size_t)(dc * 64 + d) * 8) = val;
    }
  }
}

// ---------------------------------------------------------------- GEMM1 (bf16)
__global__ __launch_bounds__(256) void gemm1(const u16* __restrict__ A,
                                             const u16* __restrict__ B,
                                             const float* __restrict__ bias,
                                             float* __restrict__ C) {
  __shared__ u16 As[2][128 * 32];
  __shared__ u16 Bs[2][128 * 32];
  int t = threadIdx.x;
  int brow = blockIdx.x * 128, bcol = blockIdx.y * 128;
  int w = t >> 6, l = t & 63;
  int l15 = l & 15, l4 = l >> 4;
  int wr = (w >> 1) * 64, wc = (w & 1) * 64;
  f32x4 acc[4][4];
#pragma unroll
  for (int i = 0; i < 4; ++i)
#pragma unroll
    for (int j = 0; j < 4; ++j) acc[i][j] = f32x4{0.f, 0.f, 0.f, 0.f};

  auto stage = [&](int buf, int kt) {
#pragma unroll
    for (int i = 0; i < 2; ++i) {
      int id = t + i * 256;
      int row = id >> 2, c = id & 3;
      int cs = (c ^ (row & 3)) * 8;
      GLL16(A + (size_t)(brow + row) * 1024 + kt * 32 + cs, &As[buf][id * 8]);
      GLL16(B + (size_t)(bcol + row) * 1024 + kt * 32 + cs, &Bs[buf][id * 8]);
    }
  };
  stage(0, 0);
  for (int kt = 0; kt < 32; ++kt) {
    int buf = kt & 1;
    __syncthreads();
    if (kt < 31) stage(buf ^ 1, kt + 1);
    bf16x8 a[4], b[4];
#pragma unroll
    for (int mf = 0; mf < 4; ++mf) {
      int row = wr + mf * 16 + l15;
      a[mf] = *(const bf16x8*)&As[buf][row * 32 + ((l4 ^ (row & 3)) * 8)];
    }
#pragma unroll
    for (int nf = 0; nf < 4; ++nf) {
      int row = wc + nf * 16 + l15;
      b[nf] = *(const bf16x8*)&Bs[buf][row * 32 + ((l4 ^ (row & 3)) * 8)];
    }
#pragma unroll
    for (int mf = 0; mf < 4; ++mf)
#pragma unroll
      for (int nf = 0; nf < 4; ++nf)
        acc[mf][nf] = __builtin_amdgcn_mfma_f32_16x16x32_bf16(a[mf], b[nf], acc[mf][nf], 0, 0, 0);
  }
#pragma unroll
  for (int mf = 0; mf < 4; ++mf)
#pragma unroll
    for (int nf = 0; nf < 4; ++nf) {
      int col = bcol + wc + nf * 16 + l15;
      float bv = bias[col];
#pragma unroll
      for (int j = 0; j < 4; ++j) {
        int row = brow + wr + mf * 16 + l4 * 4 + j;
        C[(size_t)row * 768 + col] = acc[mf][nf][j] + bv;
      }
    }
}

// ---------------------------------------------------------------- row L2-normalize -> fp8
__global__ __launch_bounds__(384) void rownorm8(const float* __restrict__ P,
                                                u8* __restrict__ pn8) {
  int row = blockIdx.x, t = threadIdx.x;
  size_t base = (size_t)row * 768;
  float2 v = *(const float2*)&P[base + 2 * t];
  float ss = v.x * v.x + v.y * v.y;
#pragma unroll
  for (int o = 32; o; o >>= 1) ss += __shfl_xor(ss, o);
  __shared__ float wsum[6];
  if ((t & 63) == 0) wsum[t >> 6] = ss;
  __syncthreads();
  float tot = wsum[0] + wsum[1] + wsum[2] + wsum[3] + wsum[4] + wsum[5];
  float inv = 1.0f / fmaxf(sqrtf(tot), 1e-12f);
  u32 pk = pk_fp8<false>(v.x * inv, v.y * inv, 0u);
  *(u16*)(pn8 + base + 2 * t) = (u16)(pk & 0xFFFFu);
}

// ---------------------------------------------------------------- fused attention, fp8
// 16 waves (1024 thr), BM=64 q, KVBLK=512 (32 keys/wave for QK), nsplit=2.
// QK: 32x32x16 fp8 (swapped, A=K from global, B=Q from LDS) -> S^T.
// PV: 16x16x32 fp8, wave d-split 48 (oacc 48 f32/lane; ~115 regs -> 4 waves/SIMD).
// Logits <= beta -> no max tracking; accumulate unnormalized O and l per split.
__global__ __launch_bounds__(1024, 4) void attn(const u8* __restrict__ pn8,
                                                const u8* __restrict__ Kf2,
                                                const u8* __restrict__ Vtf,
                                                const float* __restrict__ beta_p,
                                                u16* __restrict__ Opart,
                                                float* __restrict__ lpart) {
  __shared__ long Qlds[96 * 64];   // 48 KB [c8][q]
  __shared__ long Ps[64 * 64];     // 32 KB [kc8][q]
  __shared__ float lred[16][64];   // 4 KB
  int t = threadIdx.x;
  int w = t >> 6, l = t & 63;
  int ql = l & 31, hi = l >> 5;        // 32x32 lanes
  int l15 = l & 15, l4g = l >> 4;      // 16x16 lanes (0..3)
  int split = blockIdx.x, qb = blockIdx.y;
  int qrow0 = qb * 64;
  float blog2e = beta_p[0] * 1.44269504089f;

  // ---- stage Q [64 q][768 d] fp8 into [c8][q] (once)
#pragma unroll
  for (int i = 0; i < 6; ++i) {
    int id = i * 1024 + t;
    int c8 = id >> 6, q = id & 63;
    Qlds[c8 * 64 + q] = *(const long*)(pn8 + (size_t)(qrow0 + q) * 768 + (size_t)c8 * 8);
  }

  f32x4 oacc[4][3];
#pragma unroll
  for (int mq = 0; mq < 4; ++mq)
#pragma unroll
    for (int nd = 0; nd < 3; ++nd) oacc[mq][nd] = f32x4{0.f, 0.f, 0.f, 0.f};
  float lsum0 = 0.f, lsum1 = 0.f;

  int kbase = split * 8192;
  const long* Kp = (const long*)Kf2 + (size_t)hi * 16384 + (size_t)(kbase + w * 32 + ql);
  const long* Vp = (const long*)Vtf + ((size_t)(kbase >> 3) + l4g) * 768 + (size_t)(w * 48 + l15);

  __syncthreads();

  for (int it = 0; it < 16; ++it) {
    int n0 = it * 512;
    const long* kp = Kp + n0;

    // ---------- QK^T: wave w -> keys [n0+w*32,+32), all 64 q
    f32x16 sacc0 = (f32x16)0.0f;
    f32x16 sacc1 = (f32x16)0.0f;
    long kbuf[6];
#pragma unroll
    for (int i = 0; i < 6; ++i) kbuf[i] = kp[(size_t)i * 32768];
#pragma unroll
    for (int ks = 0; ks < 48; ++ks) {
      long kv = kbuf[ks % 6];
      if (ks < 42) kbuf[ks % 6] = kp[(size_t)(ks + 6) * 32768];
      long q0 = Qlds[(ks * 2 + hi) * 64 + ql];
      long q1 = Qlds[(ks * 2 + hi) * 64 + ql + 32];
      sacc0 = __builtin_amdgcn_mfma_f32_32x32x16_fp8_fp8(kv, q0, sacc0, 0, 0, 0);
      sacc1 = __builtin_amdgcn_mfma_f32_32x32x16_fp8_fp8(kv, q1, sacc1, 0, 0, 0);
    }

    // ---------- exp (no max), lsum, pack fp8 -> Ps [kc8][q]
#pragma unroll
    for (int qf = 0; qf < 2; ++qf) {
      int q = ql + qf * 32;
      float lacc = 0.f;
#pragma unroll
      for (int rg = 0; rg < 4; ++rg) {
        float p0, p1, p2, p3;
        if (qf == 0) {
          p0 = exp2f(blog2e * sacc0[rg * 4 + 0]); p1 = exp2f(blog2e * sacc0[rg * 4 + 1]);
          p2 = exp2f(blog2e * sacc0[rg * 4 + 2]); p3 = exp2f(blog2e * sacc0[rg * 4 + 3]);
        } else {
          p0 = exp2f(blog2e * sacc1[rg * 4 + 0]); p1 = exp2f(blog2e * sacc1[rg * 4 + 1]);
          p2 = exp2f(blog2e * sacc1[rg * 4 + 2]); p3 = exp2f(blog2e * sacc1[rg * 4 + 3]);
        }
        lacc += (p0 + p1) + (p2 + p3);
        u32 pk = pk_fp8<false>(p0, p1, 0u); pk = pk_fp8<true>(p2, p3, pk);
        ((u32*)Ps)[(w * 4 + rg) * 128 + q * 2 + hi] = pk;
      }
      if (qf == 0) lsum0 += lacc; else lsum1 += lacc;
    }
    BARRIER_LGKM();   // P visible to all waves

    // ---------- PV: O[64 q][48 d per wave] += P * V  (16x16x32)
    long vbuf[2][3];
#pragma unroll
    for (int kc = 0; kc < 2; ++kc)
#pragma unroll
      for (int nd = 0; nd < 3; ++nd)
        vbuf[kc][nd] = Vp[((size_t)(n0 >> 3) + kc * 4) * 768 + nd * 16];
#pragma unroll
    for (int kc = 0; kc < 16; ++kc) {
      long v0 = vbuf[kc & 1][0], v1 = vbuf[kc & 1][1], v2 = vbuf[kc & 1][2];
      if (kc < 14) {
#pragma unroll
        for (int nd = 0; nd < 3; ++nd)
          vbuf[kc & 1][nd] = Vp[((size_t)(n0 >> 3) + (kc + 2) * 4) * 768 + nd * 16];
      }
#pragma unroll
      for (int mq = 0; mq < 4; ++mq) {
        long pa = Ps[(kc * 4 + l4g) * 64 + mq * 16 + l15];
        oacc[mq][0] = __builtin_amdgcn_mfma_f32_16x16x32_fp8_fp8(pa, v0, oacc[mq][0], 0, 0, 0);
        oacc[mq][1] = __builtin_amdgcn_mfma_f32_16x16x32_fp8_fp8(pa, v1, oacc[mq][1], 0, 0, 0);
        oacc[mq][2] = __builtin_amdgcn_mfma_f32_16x16x32_fp8_fp8(pa, v2, oacc[mq][2], 0, 0, 0);
      }
    }
    BARRIER_LGKM();   // Ps reads drained before next iter rewrites
  }

  // ---- l reduction: lanes l, l^32 share q; wave covers its 32 keys
  {
    float s0 = lsum0 + __shfl_xor(lsum0, 32);
    float s1 = lsum1 + __shfl_xor(lsum1, 32);
    if (hi == 0) { lred[w][ql] = s0; lred[w][ql + 32] = s1; }
  }
  __syncthreads();
  if (t < 64) {
    float s = 0.f;
#pragma unroll
    for (int ww = 0; ww < 16; ++ww) s += lred[ww][t];
    lpart[split * 8192 + qrow0 + t] = s;
  }

  // ---- write unnormalized O partial (bf16)
#pragma unroll
  for (int mq = 0; mq < 4; ++mq)
#pragma unroll
    for (int nd = 0; nd < 3; ++nd) {
      int col = w * 48 + nd * 16 + l15;
#pragma unroll
      for (int j = 0; j < 4; ++j) {
        int row = qrow0 + mq * 16 + l4g * 4 + j;
        Opart[((size_t)split * 8192 + row) * 768 + col] = f2bf(oacc[mq][nd][j]);
      }
    }
}

// ---------------------------------------------------------------- final combine
__global__ __launch_bounds__(192) void combine(float* __restrict__ out,
                                               const u16* __restrict__ Opart,
                                               const float* __restrict__ lpart,
                                               const float* __restrict__ alpha_p) {
  int row = blockIdx.x, t = threadIdx.x;
  float scale = alpha_p[0] / (lpart[row] + lpart[8192 + row]);
  size_t base = (size_t)row * 768 + t * 4;
  u16x4 o0 = *(const u16x4*)&Opart[base];
  u16x4 o1 = *(const u16x4*)&Opart[(size_t)6291456 + base];
  float4 cur = *(float4*)&out[base];
  union { u32 u; float f; } c0, c1, c2, c3, d0_, d1_, d2_, d3_;
  c0.u = (u32)o0[0] << 16; c1.u = (u32)o0[1] << 16; c2.u = (u32)o0[2] << 16; c3.u = (u32)o0[3] << 16;
  d0_.u = (u32)o1[0] << 16; d1_.u = (u32)o1[1] << 16; d2_.u = (u32)o1[2] << 16; d3_.u = (u32)o1[3] << 16;
  cur.x += (c0.f + d0_.f) * scale;
  cur.y += (c1.f + d1_.f) * scale;
  cur.z += (c2.f + d2_.f) * scale;
  cur.w += (c3.f + d3_.f) * scale;
  *(float4*)&out[base] = cur;
}

// ---------------------------------------------------------------- launch
extern "C" void kernel_launch(void* const* d_in, const int* in_sizes, int n_in,
                              void* d_out, int out_size, void* d_ws, size_t ws_size,
                              hipStream_t stream) {
  const float* x      = (const float*)d_in[0];   // [8192][1024]
  const float* W      = (const float*)d_in[1];   // [768][1024]
  const float* bias   = (const float*)d_in[2];   // [768]
  const float* keys   = (const float*)d_in[3];   // [16384][768]
  const float* values = (const float*)d_in[4];   // [16384][768]
  const float* beta   = (const float*)d_in[5];
  const float* alpha  = (const float*)d_in[6];
  float* out = (float*)d_out;

  char* ws = (char*)d_ws;
  u16* xb    = (u16*)(ws + 0);            // 16,777,216 B
  u16* Wb    = (u16*)(ws + 16777216);     //  1,572,864 B
  u8*  Kf2   = (u8*) (ws + 18350080);     // 12,582,912 B
  u8*  Vtf   = (u8*) (ws + 30932992);     // 12,582,912 B
  u8*  pn8   = (u8*) (ws + 43515904);     //  6,291,456 B
  u16* Opart = (u16*)(ws + 49807360);     // 25,165,824 B
  float* lp  = (float*)(ws + 74973184);   //     65,536 B   (total 75,038,720)

  cvt_bf16<<<2048, 256, 0, stream>>>(x, xb, 8192 * 1024 / 4);
  cvt_bf16<<<768, 256, 0, stream>>>(W, Wb, 768 * 1024 / 4);
  buildK<<<256, 256, 0, stream>>>(keys, Kf2);
  buildV<<<256, 256, 0, stream>>>(values, Vtf);
  gemm1<<<dim3(64, 6), 256, 0, stream>>>(xb, Wb, bias, out);
  rownorm8<<<8192, 384, 0, stream>>>(out, pn8);
  attn<<<dim3(2, 128), 1024, 0, stream>>>(pn8, Kf2, Vtf, beta, Opart, lp);
  combine<<<8192, 192, 0, stream>>>(out, Opart, lp, alpha);
}